// Round 1
// baseline (101.681 us; speedup 1.0000x reference)
//
#include <hip/hip_runtime.h>

// Problem constants
#define IN_DIM   512
#define OUT_DIM  512
#define KDEG     3
#define BATCH    256
#define NB       19                 // spline basis count per input dim
#define NG       23                 // grid points per input dim
#define KAUG     20                 // 19 spline slots + 1 base(silu) slot
#define KTOT     (IN_DIM * KAUG)    // 10240

typedef short  bf16x8 __attribute__((ext_vector_type(8)));   // 8 bf16 = 4 VGPRs
typedef short  bf16x4 __attribute__((ext_vector_type(4)));   // 4 bf16 = 2 VGPRs
typedef float  f32x4  __attribute__((ext_vector_type(4)));

// round-to-nearest-even fp32 -> bf16
__device__ __forceinline__ unsigned short f2bf(float f) {
    union { float f; unsigned int u; } v; v.f = f;
    unsigned int r = (v.u + 0x7FFF + ((v.u >> 16) & 1)) >> 16;
    return (unsigned short)r;
}

__device__ __forceinline__ float bf2f(unsigned short h) {
    union { unsigned int u; float f; } v;
    v.u = ((unsigned int)h) << 16;
    return v.f;
}

// ---------------------------------------------------------------------------
// Kernel 1: augmented A (BATCH x KTOT), bf16, k-contiguous.
// Change vs prev: shared reciprocal trick — d2(kk,j) == d1(kk,j+1), so build
// one inv[] table per kk (63 divides total) instead of 120 inline fdivs.
// ---------------------------------------------------------------------------
__global__ void build_A(const float* __restrict__ X,
                        const float* __restrict__ G,
                        unsigned short* __restrict__ A) {
    int t = blockIdx.x * blockDim.x + threadIdx.x;
    if (t >= BATCH * IN_DIM) return;
    int b = t >> 9;            // / IN_DIM
    int i = t & (IN_DIM - 1);

    float x = X[t];

    float gr[NG];
    const float* g = G + i * NG;
#pragma unroll
    for (int j = 0; j < NG; j++) gr[j] = g[j];

    float B[NG - 1];
#pragma unroll
    for (int j = 0; j < NG - 1; j++)
        B[j] = (x >= gr[j] && x < gr[j + 1]) ? 1.0f : 0.0f;

#pragma unroll
    for (int kk = 1; kk <= KDEG; kk++) {
        float inv[NG];
#pragma unroll
        for (int j = 0; j < NG - kk; j++)
            inv[j] = 1.0f / (gr[j + kk] - gr[j]);
#pragma unroll
        for (int j = 0; j < NG - 1 - kk; j++)
            B[j] = (x - gr[j]) * inv[j] * B[j] +
                   (gr[j + kk + 1] - x) * inv[j + 1] * B[j + 1];
    }

    unsigned short v[KAUG];
#pragma unroll
    for (int j = 0; j < NB; j++) v[j] = f2bf(B[j]);
    v[NB] = f2bf(x / (1.0f + __expf(-x)));   // silu

    unsigned int* dst = (unsigned int*)(A + (size_t)b * KTOT + i * KAUG);
    const unsigned int* src = (const unsigned int*)v;
#pragma unroll
    for (int d = 0; d < KAUG / 2; d++) dst[d] = src[d];
}

// ---------------------------------------------------------------------------
// Kernel 2 (fused W-build + split-K GEMM -> bf16 partials).
// Changes vs prev:
//  (a) coef slab is staged into LDS with COALESCED dword loads (prev: 19
//      scalar loads at 76B lane stride = ~38 L1 lines per instruction).
//  (b) 1-D grid + bijective XCD swizzle: all 16 o-blocks that share one
//      z-split's A-chunk (164 KB) land on the same XCD -> A stays L2-resident
//      instead of being refetched through L3 by every XCD.
// Geometry unchanged: 512 blocks, 512 threads (8 waves), BM=256, BN=32,
// ICH=16 -> KCH=320, one compute barrier.
// ---------------------------------------------------------------------------
#define BN     32
#define SPLITS 32
#define ICH    16                  // i's per block
#define KCH    (ICH * KAUG)        // 320
#define LDS_K  (KCH + 8)           // 328 elems -> row stride 656B
#define SLAB   (BN * NB)           // 608 floats per i-run

__global__ __launch_bounds__(512, 4) void gemm_fused(
        const unsigned short* __restrict__ A,
        const float* __restrict__ coef,
        const float* __restrict__ scale_sp,
        const float* __restrict__ mask,
        unsigned short* __restrict__ P) {
    __shared__ __align__(16) unsigned short Bs[BN * LDS_K];   // 20992 B
    __shared__ __align__(16) float stag[ICH][SLAB];           // 38912 B

    int tid = threadIdx.x;

    // XCD swizzle: linear -> (z, o-block) so that the 16 blocks sharing an
    // A z-chunk are all congruent mod 8 (same XCD under round-robin).
    // Bijective: linear = (z%4)*128 + ob*8 + z/4.
    int linear = blockIdx.x;                      // 0..511
    int z  = ((linear & 7) << 2) + (linear >> 7); // 0..31
    int ob = (linear >> 3) & 15;                  // 0..15
    int o0 = ob * BN;
    int i0 = z * ICH;
    int kbase = z * KCH;

    // per-thread (i,o) assignment for the W-build gather
    int o  = tid & 31;         // lanes sweep o -> coalesced mask/scale
    int di = tid >> 5;         // 0..15
    int io = (i0 + di) * OUT_DIM + (o0 + o);
    float m  = mask[io];                 // issued early, overlaps staging
    float sm = scale_sp[io] * m;

    // ---- stage coef slab: 16 runs x 608 contiguous floats, coalesced ------
    {
        const float* cbase = coef + ((size_t)i0 * OUT_DIM + o0) * NB;
#pragma unroll
        for (int r = 0; r < ICH; ++r) {
            const float* run = cbase + (size_t)r * OUT_DIM * NB;
            stag[r][tid] = run[tid];
            if (tid < SLAB - 512) stag[r][512 + tid] = run[512 + tid];
        }
    }
    __syncthreads();

    // ---- build Bs from LDS slab (stride-19 gather: 19 coprime 32 ->
    //      conflict-free; di pairs give free 2-way aliasing) ----------------
    {
        const float* cs = &stag[di][o * NB];
        __align__(8) unsigned short v[KAUG];
#pragma unroll
        for (int g2 = 0; g2 < NB; g2++) v[g2] = f2bf(cs[g2] * sm);
        v[NB] = f2bf(m);           // silu-slot weight

        unsigned long long* dst =
            (unsigned long long*)((char*)Bs + (size_t)o * (LDS_K * 2) + di * (KAUG * 2));
        const unsigned long long* src = (const unsigned long long*)v;
#pragma unroll
        for (int d = 0; d < 5; d++) dst[d] = src[d];
    }
    __syncthreads();

    // ---- compute phase: barrier-free unrolled K-loop ----------------------
    int lane = tid & 63;
    int w    = tid >> 6;           // wave 0..7, owns m-strip [32w, 32w+32)
    int quad = lane >> 4;
    int lr   = lane & 15;

    f32x4 acc[2][2];
#pragma unroll
    for (int i = 0; i < 2; i++)
#pragma unroll
        for (int j = 0; j < 2; j++) acc[i][j] = (f32x4)0.0f;

    const unsigned short* a0 = A + (size_t)(w * 32 + lr)      * KTOT + kbase + quad * 8;
    const unsigned short* a1 = A + (size_t)(w * 32 + 16 + lr) * KTOT + kbase + quad * 8;
    const unsigned short* b0 = &Bs[(size_t)lr        * LDS_K + quad * 8];
    const unsigned short* b1 = &Bs[(size_t)(16 + lr) * LDS_K + quad * 8];

#pragma unroll
    for (int kk = 0; kk < KCH; kk += 32) {
        bf16x8 af0 = *(const bf16x8*)(a0 + kk);
        bf16x8 af1 = *(const bf16x8*)(a1 + kk);
        bf16x8 bf0 = *(const bf16x8*)(b0 + kk);
        bf16x8 bf1 = *(const bf16x8*)(b1 + kk);
        acc[0][0] = __builtin_amdgcn_mfma_f32_16x16x32_bf16(af0, bf0, acc[0][0], 0, 0, 0);
        acc[0][1] = __builtin_amdgcn_mfma_f32_16x16x32_bf16(af0, bf1, acc[0][1], 0, 0, 0);
        acc[1][0] = __builtin_amdgcn_mfma_f32_16x16x32_bf16(af1, bf0, acc[1][0], 0, 0, 0);
        acc[1][1] = __builtin_amdgcn_mfma_f32_16x16x32_bf16(af1, bf1, acc[1][1], 0, 0, 0);
    }

    // ---- epilogue: bf16 stores into per-split partial buffer --------------
    // C/D layout: col=lane&15, row=quad*4+reg
    unsigned short* Pz = P + (size_t)z * BATCH * OUT_DIM;
#pragma unroll
    for (int mt = 0; mt < 2; mt++) {
#pragma unroll
        for (int nt = 0; nt < 2; nt++) {
            int col = o0 + nt * 16 + lr;
            int rb  = w * 32 + mt * 16 + quad * 4;
#pragma unroll
            for (int r = 0; r < 4; r++)
                Pz[(size_t)(rb + r) * OUT_DIM + col] = f2bf(acc[mt][nt][r]);
        }
    }
}

// ---------------------------------------------------------------------------
// Kernel 3: reduce bf16 partials: out[e] = sum_z P[z][e].
// Change vs prev: 4 outputs/thread (8B loads) -> 128 blocks instead of 64;
// doubles active CUs on this HBM-latency/BW-bound pass.
// ---------------------------------------------------------------------------
__global__ __launch_bounds__(256) void reduce_out(const unsigned short* __restrict__ P,
                                                  float* __restrict__ out) {
    int e4 = blockIdx.x * blockDim.x + threadIdx.x;   // 0 .. 32767
    float s0 = 0.f, s1 = 0.f, s2 = 0.f, s3 = 0.f;
#pragma unroll
    for (int zz = 0; zz < SPLITS; zz++) {
        bf16x4 v = *(const bf16x4*)(P + (size_t)zz * BATCH * OUT_DIM + (size_t)e4 * 4);
        s0 += bf2f((unsigned short)v[0]);
        s1 += bf2f((unsigned short)v[1]);
        s2 += bf2f((unsigned short)v[2]);
        s3 += bf2f((unsigned short)v[3]);
    }
    f32x4 r = { s0, s1, s2, s3 };
    *(f32x4*)(out + (size_t)e4 * 4) = r;
}

// ---------------------------------------------------------------------------
extern "C" void kernel_launch(void* const* d_in, const int* in_sizes, int n_in,
                              void* d_out, int out_size, void* d_ws, size_t ws_size,
                              hipStream_t stream) {
    const float* x        = (const float*)d_in[0];   // (256, 512)
    const float* grid     = (const float*)d_in[1];   // (512, 23)
    const float* coef     = (const float*)d_in[2];   // (512, 512, 19)
    const float* scale_sp = (const float*)d_in[3];   // (512, 512)
    const float* mask     = (const float*)d_in[4];   // (512, 512)
    float* out = (float*)d_out;                      // (256, 512)

    unsigned short* A = (unsigned short*)d_ws;                              // 5.24 MB
    unsigned short* P = (unsigned short*)((char*)d_ws + (size_t)BATCH * KTOT * 2); // 8.39 MB

    build_A<<<dim3((BATCH * IN_DIM + 255) / 256), dim3(256), 0, stream>>>(x, grid, A);

    gemm_fused<<<dim3(OUT_DIM / BN * SPLITS), dim3(512), 0, stream>>>(
        A, coef, scale_sp, mask, P);

    reduce_out<<<dim3(BATCH * OUT_DIM / 4 / 256), dim3(256), 0, stream>>>(P, out);
}